// Round 1
// baseline (176.855 us; speedup 1.0000x reference)
//
#include <hip/hip_runtime.h>

// VectorQuantizer: x [2,8,48,48,48] f32, embed [512,8] f32
// outputs: loss (1) | out [2,8,48,48,48] (1769472) | encodings [221184,512] (113246208)

#pragma clang fp contract(off)

#define KCB   512
#define DIM   8
#define SPB   110592          // 48*48*48 (spatial per batch)
#define NPTS  221184          // 2*SPB
#define NBLK  864             // NPTS/256
#define OUT_OFF 1
#define ENC_OFF 1769473       // 1 + 2*8*SPB
// enc region per block: 131072 floats starting at ENC_OFF + blockIdx*131072
// alignment: ENC_OFF % 4 == 1 -> 3 head scalars, 32767 float4, 1 tail scalar
// first aligned float4 index (in float4 units from d_out base):
#define G4_BASE 442369        // (ENC_OFF + 3) / 4

__global__ __launch_bounds__(256) void se_kernel(const float* __restrict__ e,
                                                 float* __restrict__ se) {
    int k = blockIdx.x * 256 + threadIdx.x;
    if (k < KCB) {
        const float4* e4 = (const float4*)(e + (k << 3));
        float4 a = e4[0], b = e4[1];
        // numpy pairwise tree over 8 squared elements, squares rounded first
        float s = ((a.x*a.x + a.y*a.y) + (a.z*a.z + a.w*a.w))
                + ((b.x*b.x + b.y*b.y) + (b.z*b.z + b.w*b.w));
        se[k] = s;
    }
}

__global__ __launch_bounds__(256) void vq_main(const float* __restrict__ x,
                                               const float* __restrict__ e,
                                               const float* __restrict__ se,
                                               float* __restrict__ dout,
                                               float* __restrict__ partials) {
    __shared__ float sred[256];
    __shared__ int   sidx[256];
    const int tid = threadIdx.x;
    const int n   = blockIdx.x * 256 + tid;   // < NPTS always (864*256)
    const int b   = n / SPB;
    const int s   = n - b * SPB;

    // load this point's 8 channels (coalesced across lanes per channel)
    const float* xb = x + (size_t)b * (8 * SPB) + s;
    float xv[8];
    #pragma unroll
    for (int c = 0; c < 8; ++c) xv[c] = xb[(size_t)c * SPB];

    // sum(x^2) with numpy's 8-element pairwise tree (contract off -> squares rounded)
    float sx = ((xv[0]*xv[0] + xv[1]*xv[1]) + (xv[2]*xv[2] + xv[3]*xv[3]))
             + ((xv[4]*xv[4] + xv[5]*xv[5]) + (xv[6]*xv[6] + xv[7]*xv[7]));

    // argmin_k  fl( fl(sx + se_k) - 2*dot_k );  strict < keeps first index
    float best = 3.402823466e38f;
    int   bidx = 0;
    for (int k = 0; k < KCB; ++k) {
        const float4* e4 = (const float4*)(e + (k << 3));  // uniform -> s_load/L1
        float4 ea = e4[0], eb = e4[1];
        float dot =      xv[0] * ea.x;
        dot = __builtin_fmaf(xv[1], ea.y, dot);
        dot = __builtin_fmaf(xv[2], ea.z, dot);
        dot = __builtin_fmaf(xv[3], ea.w, dot);
        dot = __builtin_fmaf(xv[4], eb.x, dot);
        dot = __builtin_fmaf(xv[5], eb.y, dot);
        dot = __builtin_fmaf(xv[6], eb.z, dot);
        dot = __builtin_fmaf(xv[7], eb.w, dot);
        float ssk = sx + se[k];                     // rounded add, matches ref
        float d   = __builtin_fmaf(-2.0f, dot, ssk); // == fl(ssk - 2*dot), 2*dot exact
        if (d < best) { best = d; bidx = k; }
    }

    // quantized values, straight-through out, loss contribution
    const float4* q4 = (const float4*)(e + (bidx << 3));
    float4 qa = q4[0], qb = q4[1];
    float qv[8] = {qa.x, qa.y, qa.z, qa.w, qb.x, qb.y, qb.z, qb.w};
    float part = 0.0f;
    float* outp = dout + OUT_OFF + (size_t)b * (8 * SPB) + s;
    #pragma unroll
    for (int c = 0; c < 8; ++c) {
        float dq = qv[c] - xv[c];
        part += dq * dq;
        outp[(size_t)c * SPB] = qv[c];
    }

    sred[tid] = part;
    sidx[tid] = bidx;
    __syncthreads();
    // deterministic fixed-order block reduction
    for (int off = 128; off > 0; off >>= 1) {
        if (tid < off) sred[tid] += sred[tid + off];
        __syncthreads();
    }
    if (tid == 0) partials[blockIdx.x] = sred[0];

    // ---- cooperative one-hot encodings write (453 MB total, float4 stores) ----
    float4* o4 = (float4*)dout;
    const int g4_start = G4_BASE + blockIdx.x * 32768;
    #pragma unroll 1
    for (int i = 0; i < 128; ++i) {
        int t_lin = i * 256 + tid;
        if (t_lin < 32767) {
            int f  = 3 + (t_lin << 2);   // float index within block's enc region
            int nl = f >> 9;             // local row 0..255
            int k0 = f & 511;
            int id0 = sidx[nl];
            float4 v;
            if (k0 != 511) {
                v.x = (id0 == k0    ) ? 1.0f : 0.0f;
                v.y = (id0 == k0 + 1) ? 1.0f : 0.0f;
                v.z = (id0 == k0 + 2) ? 1.0f : 0.0f;
                v.w = (id0 == k0 + 3) ? 1.0f : 0.0f;
            } else {                      // crosses a row boundary
                int id1 = sidx[nl + 1];
                v.x = (id0 == 511) ? 1.0f : 0.0f;
                v.y = (id1 == 0  ) ? 1.0f : 0.0f;
                v.z = (id1 == 1  ) ? 1.0f : 0.0f;
                v.w = (id1 == 2  ) ? 1.0f : 0.0f;
            }
            o4[(size_t)g4_start + t_lin] = v;
        }
    }
    // unaligned head (cols 0..2 of first row) and tail (col 511 of last row)
    const long long gbase = (long long)ENC_OFF + (long long)blockIdx.x * 131072;
    if (tid == 0) {
        int id = sidx[0];
        dout[gbase + 0] = (id == 0) ? 1.0f : 0.0f;
        dout[gbase + 1] = (id == 1) ? 1.0f : 0.0f;
        dout[gbase + 2] = (id == 2) ? 1.0f : 0.0f;
    } else if (tid == 1) {
        int id = sidx[255];
        dout[gbase + 131071] = (id == 511) ? 1.0f : 0.0f;
    }
}

__global__ __launch_bounds__(256) void loss_kernel(const float* __restrict__ partials,
                                                   float* __restrict__ dout) {
    __shared__ float sred[256];
    int t = threadIdx.x;
    float a = 0.0f;
    for (int j = t; j < NBLK; j += 256) a += partials[j];  // fixed order: deterministic
    sred[t] = a;
    __syncthreads();
    for (int off = 128; off > 0; off >>= 1) {
        if (t < off) sred[t] += sred[t + off];
        __syncthreads();
    }
    if (t == 0) {
        float m = sred[0] / 1769472.0f;                 // mean((q - x)^2)
        m = fminf(fmaxf(m, 0.0f), 10.0f);               // clip [0,10]
        dout[0] = m + 0.25f * m;                        // q_latent + beta*e_latent
    }
}

extern "C" void kernel_launch(void* const* d_in, const int* in_sizes, int n_in,
                              void* d_out, int out_size, void* d_ws, size_t ws_size,
                              hipStream_t stream) {
    const float* x = (const float*)d_in[0];
    const float* e = (const float*)d_in[1];
    float* dout = (float*)d_out;
    float* se       = (float*)d_ws;       // 512 floats
    float* partials = se + 512;           // 864 floats
    hipLaunchKernelGGL(se_kernel, dim3(2),    dim3(256), 0, stream, e, se);
    hipLaunchKernelGGL(vq_main,   dim3(NBLK), dim3(256), 0, stream, x, e, se, dout, partials);
    hipLaunchKernelGGL(loss_kernel, dim3(1),  dim3(256), 0, stream, partials, dout);
}